// Round 1
// baseline (183.182 us; speedup 1.0000x reference)
//
#include <hip/hip_runtime.h>
#include <stdint.h>

typedef unsigned short u16;
typedef u16 u16x4 __attribute__((ext_vector_type(4)));
typedef u16 u16x8 __attribute__((ext_vector_type(8)));
typedef __bf16 bf16x8 __attribute__((ext_vector_type(8)));
typedef float f32x4 __attribute__((ext_vector_type(4)));

#define NSER 4096
#define KDIM 4096
#define NCOLS 288                 // 264 padded to 288 (divisible by BN=96)
#define MATSZ (NCOLS * NSER)      // elements per transposed mat buffer

__device__ __forceinline__ u16 f2bf(float f) {
  uint32_t u = __builtin_bit_cast(uint32_t, f);
  u += 0x7FFFu + ((u >> 16) & 1u);   // RNE; inputs are never NaN
  return (u16)(u >> 16);
}
__device__ __forceinline__ float bf2f(u16 h) {
  return __builtin_bit_cast(float, (uint32_t)h << 16);
}

typedef const void __attribute__((address_space(1)))* gas1p;
typedef void __attribute__((address_space(3)))* las3p;

__device__ __forceinline__ void gload16(const void* g, void* l) {
  __builtin_amdgcn_global_load_lds((gas1p)g, (las3p)l, 16, 0, 0);
}

// ---------------- convert supports fp32 -> bf16 ----------------
__global__ __launch_bounds__(256) void k_convert(const float* __restrict__ s0,
                                                 const float* __restrict__ s1,
                                                 u16* __restrict__ d0,
                                                 u16* __restrict__ d1) {
  const float* src = blockIdx.z ? s1 : s0;
  u16* dst = blockIdx.z ? d1 : d0;
  const int i = (blockIdx.x * 256 + threadIdx.x) * 8;
  float4 a = *(const float4*)(src + i);
  float4 b = *(const float4*)(src + i + 4);
  u16x8 o;
  o[0] = f2bf(a.x); o[1] = f2bf(a.y); o[2] = f2bf(a.z); o[3] = f2bf(a.w);
  o[4] = f2bf(b.x); o[5] = f2bf(b.y); o[6] = f2bf(b.z); o[7] = f2bf(b.w);
  *(u16x8*)(dst + i) = o;
}

// ---------------- build X^T [288][4096] bf16 ----------------
// Xt[f*4+b][n] = xs[b,n,f];  f<2 -> inputs[b][n*2+f], f>=2 -> state[b][n*64+(f-2)]
__global__ __launch_bounds__(256) void k_build_x(const float* __restrict__ inputs,
                                                 const float* __restrict__ state,
                                                 u16* __restrict__ xb) {
  __shared__ float tile[64][65];
  const int nt = blockIdx.x, b = blockIdx.y;
  const int n0 = nt * 64;
  const int t = threadIdx.x;
  {
    const int i = t >> 2;
    const int c0 = (t & 3) * 16;
    const float* sp = state + ((int64_t)b * NSER + (n0 + i)) * 64 + c0;
    #pragma unroll
    for (int q = 0; q < 4; ++q) {
      float4 v = *(const float4*)(sp + q * 4);
      tile[i][c0 + q * 4 + 0] = v.x;
      tile[i][c0 + q * 4 + 1] = v.y;
      tile[i][c0 + q * 4 + 2] = v.z;
      tile[i][c0 + q * 4 + 3] = v.w;
    }
  }
  __syncthreads();
  const int wv = t >> 6, lane = t & 63;
  #pragma unroll
  for (int it = 0; it < 16; ++it) {
    const int d = wv + 4 * it;  // 0..63
    xb[(size_t)((2 + d) * 4 + b) * NSER + n0 + lane] = f2bf(tile[lane][d]);
  }
  if (t < 128) {
    const int c = t >> 6, j = t & 63;
    xb[(size_t)(c * 4 + b) * NSER + n0 + j] =
        f2bf(inputs[(int64_t)b * (NSER * 2) + (int64_t)(n0 + j) * 2 + c]);
  }
  if (b == 0) {  // zero pad rows 264..287
    for (int idx = t; idx < 24 * 64; idx += 256)
      xb[(size_t)(264 + idx / 64) * NSER + n0 + (idx & 63)] = 0;
  }
}

// ---------------- GEMM: C^T[j][i] = sum_k A[i][k] * B^T[j][k] (all bf16) ----------------
#define BM 128
#define BN 96
#define BK 64
#define NKT (KDIM / BK)
#define ABYTES (BM * BK * 2)      // 16384
#define BBYTES (BN * BK * 2)      // 12288
#define BUFSZ  (ABYTES + BBYTES)  // 28672

__global__ __launch_bounds__(256) void k_gemm(const u16* __restrict__ A0,
                                              const u16* __restrict__ A1,
                                              const u16* __restrict__ Bm,
                                              u16* __restrict__ C0,
                                              u16* __restrict__ C1) {
  const u16* Am = blockIdx.z ? A1 : A0;
  u16* Cm = blockIdx.z ? C1 : C0;
  const int i0 = blockIdx.x * BM;   // row-tile fastest -> col-blocks of same A panel share XCD
  const int j0 = blockIdx.y * BN;
  const int t = threadIdx.x;
  const int wid = t >> 6, lane = t & 63;

  __shared__ char smem[2 * BUFSZ];

  // staging source offsets (pre-swizzled global source, linear LDS dest)
  int a_src[4];
  #pragma unroll
  for (int s = 0; s < 4; ++s) {
    const int row = (wid * 4 + s) * 8 + (lane >> 3);        // 0..127
    a_src[s] = row * (KDIM * 2) + 16 * ((lane & 7) ^ (row & 7));
  }
  int b_src[3];
  #pragma unroll
  for (int s = 0; s < 3; ++s) {
    const int row = (wid * 3 + s) * 8 + (lane >> 3);        // 0..95
    b_src[s] = row * (KDIM * 2) + 16 * ((lane & 7) ^ (row & 7));
  }
  const char* Agbase = (const char*)Am + (int64_t)i0 * (KDIM * 2);
  const char* Bgbase = (const char*)Bm + (int64_t)j0 * (KDIM * 2);

  // fragment LDS read offsets (swizzled)
  int aoffs[4], axors[4];
  #pragma unroll
  for (int mf = 0; mf < 4; ++mf) {
    const int row = (wid >> 1) * 64 + mf * 16 + (lane & 15);
    aoffs[mf] = row * 128;
    axors[mf] = (row & 7) << 4;
  }
  int boffs[3], bxors[3];
  #pragma unroll
  for (int nf = 0; nf < 3; ++nf) {
    const int row = (wid & 1) * 48 + nf * 16 + (lane & 15);
    boffs[nf] = ABYTES + row * 128;
    bxors[nf] = (row & 7) << 4;
  }
  const int klane = (lane >> 4) * 16;

  f32x4 acc[4][3];
  #pragma unroll
  for (int mf = 0; mf < 4; ++mf)
    #pragma unroll
    for (int nf = 0; nf < 3; ++nf)
      acc[mf][nf] = (f32x4){0.f, 0.f, 0.f, 0.f};

  // prologue stage kt=0 into buf 0
  #pragma unroll
  for (int s = 0; s < 4; ++s)
    gload16(Agbase + a_src[s], smem + (wid * 4 + s) * 1024);
  #pragma unroll
  for (int s = 0; s < 3; ++s)
    gload16(Bgbase + b_src[s], smem + ABYTES + (wid * 3 + s) * 1024);
  __syncthreads();

  for (int kt = 0; kt < NKT; ++kt) {
    const int cur = kt & 1;
    if (kt + 1 < NKT) {
      const char* Ak = Agbase + (kt + 1) * (BK * 2);
      const char* Bk = Bgbase + (kt + 1) * (BK * 2);
      char* sbuf = smem + (cur ^ 1) * BUFSZ;
      #pragma unroll
      for (int s = 0; s < 4; ++s)
        gload16(Ak + a_src[s], sbuf + (wid * 4 + s) * 1024);
      #pragma unroll
      for (int s = 0; s < 3; ++s)
        gload16(Bk + b_src[s], sbuf + ABYTES + (wid * 3 + s) * 1024);
    }
    const char* sb = smem + cur * BUFSZ;
    #pragma unroll
    for (int kk = 0; kk < 2; ++kk) {
      const int kb = kk * 64 + klane;
      bf16x8 af[4], bfv[3];
      #pragma unroll
      for (int mf = 0; mf < 4; ++mf)
        af[mf] = *(const bf16x8*)(sb + aoffs[mf] + (kb ^ axors[mf]));
      #pragma unroll
      for (int nf = 0; nf < 3; ++nf)
        bfv[nf] = *(const bf16x8*)(sb + boffs[nf] + (kb ^ bxors[nf]));
      #pragma unroll
      for (int mf = 0; mf < 4; ++mf)
        #pragma unroll
        for (int nf = 0; nf < 3; ++nf)
          acc[mf][nf] = __builtin_amdgcn_mfma_f32_16x16x32_bf16(af[mf], bfv[nf],
                                                                acc[mf][nf], 0, 0, 0);
    }
    __syncthreads();
  }

  // epilogue: write C^T[j][i] as bf16 (C/D frag: col=lane&15, row=(lane>>4)*4+r)
  #pragma unroll
  for (int mf = 0; mf < 4; ++mf) {
    const int i = i0 + (wid >> 1) * 64 + mf * 16 + ((lane >> 4) << 2);
    #pragma unroll
    for (int nf = 0; nf < 3; ++nf) {
      const int j = j0 + (wid & 1) * 48 + nf * 16 + (lane & 15);
      u16x4 w;
      #pragma unroll
      for (int r = 0; r < 4; ++r) w[r] = f2bf(acc[mf][nf][r]);
      *(u16x4*)(Cm + (size_t)j * NSER + i) = w;
    }
  }
}

// ---------------- final: out[b,n,o] = sum_{f,mat} Yt_mat[f*4+b][n] * W'[f*5+mat][o] + bias ----------------
__global__ __launch_bounds__(256) void k_final(const float* __restrict__ weight,
                                               const float* __restrict__ biases,
                                               const u16* __restrict__ mats,
                                               float* __restrict__ out) {
  __shared__ float w2[330][32];
  const int nt = blockIdx.x, b = blockIdx.y, oh = blockIdx.z;
  const int n0 = nt * 64;
  const int t = threadIdx.x;
  const int lane = t & 63, wv = t >> 6;
  {
    const int ol = t & 31;
    const int o = oh * 32 + ol;
    for (int f = t >> 5; f < 66; f += 8) {
      const float v0 = weight[(f * 5 + 0) * 64 + o];
      const float v1 = weight[(f * 5 + 1) * 64 + o];
      const float v2 = weight[(f * 5 + 2) * 64 + o];
      const float v3 = weight[(f * 5 + 3) * 64 + o];
      const float v4 = weight[(f * 5 + 4) * 64 + o];
      w2[f * 5 + 0][ol] = v0 - v2;   // X coefficient
      w2[f * 5 + 1][ol] = v1 - v4;   // m1
      w2[f * 5 + 2][ol] = 2.f * v2;  // m2
      w2[f * 5 + 3][ol] = v3;        // m3
      w2[f * 5 + 4][ol] = 2.f * v4;  // m4
    }
  }
  __syncthreads();
  const int ob = oh * 32 + wv * 8;
  float acc[8];
  #pragma unroll
  for (int i = 0; i < 8; ++i) acc[i] = biases[ob + i];
  for (int f = 0; f < 66; ++f) {
    #pragma unroll
    for (int mat = 0; mat < 5; ++mat) {
      const float y = bf2f(mats[(size_t)mat * MATSZ + (size_t)(f * 4 + b) * NSER + n0 + lane]);
      const float* wr = &w2[f * 5 + mat][wv * 8];
      #pragma unroll
      for (int i = 0; i < 8; ++i) acc[i] = fmaf(y, wr[i], acc[i]);
    }
  }
  float* op = out + (size_t)b * (NSER * 64) + (size_t)(n0 + lane) * 64 + ob;
  #pragma unroll
  for (int i = 0; i < 8; ++i) op[i] = acc[i];
}

extern "C" void kernel_launch(void* const* d_in, const int* in_sizes, int n_in,
                              void* d_out, int out_size, void* d_ws, size_t ws_size,
                              hipStream_t stream) {
  const float* inputs = (const float*)d_in[0];
  const float* state  = (const float*)d_in[1];
  const float* s0     = (const float*)d_in[2];
  const float* s1     = (const float*)d_in[3];
  const float* weight = (const float*)d_in[4];
  const float* biases = (const float*)d_in[5];
  float* out = (float*)d_out;

  char* ws = (char*)d_ws;
  u16* S0b = (u16*)ws;                                  // 33,554,432 B
  u16* S1b = (u16*)(ws + (size_t)33554432);             // 33,554,432 B
  u16* Xb  = (u16*)(ws + (size_t)67108864);             // 5 mats x 2,359,296 B
  u16* m1b = Xb  + MATSZ;
  u16* m2b = m1b + MATSZ;
  u16* m3b = m2b + MATSZ;
  u16* m4b = m3b + MATSZ;

  k_convert<<<dim3(8192, 1, 2), 256, 0, stream>>>(s0, s1, S0b, S1b);
  k_build_x<<<dim3(64, 4, 1), 256, 0, stream>>>(inputs, state, Xb);
  // m1 = S0 @ X
  k_gemm<<<dim3(32, 3, 1), 256, 0, stream>>>(S0b, S0b, Xb, m1b, m1b);
  // m2 = S0 @ m1 ; m3 = S1 @ m1 (fused via z)
  k_gemm<<<dim3(32, 3, 2), 256, 0, stream>>>(S0b, S1b, m1b, m2b, m3b);
  // m4 = S1 @ m3
  k_gemm<<<dim3(32, 3, 1), 256, 0, stream>>>(S1b, S1b, m3b, m4b, m4b);
  // epilogue GEMM with folded Chebyshev combinations
  k_final<<<dim3(64, 4, 2), 256, 0, stream>>>(weight, biases, Xb, out);
}

// Round 2
// 151.713 us; speedup vs baseline: 1.2074x; 1.2074x over previous
//
#include <hip/hip_runtime.h>
#include <stdint.h>

typedef unsigned short u16;
typedef u16 u16x4 __attribute__((ext_vector_type(4)));
typedef u16 u16x8 __attribute__((ext_vector_type(8)));
typedef __bf16 bf16x8 __attribute__((ext_vector_type(8)));
typedef float f32x4 __attribute__((ext_vector_type(4)));

#define NSER 4096
#define KDIM 4096
#define NCOLS 288                 // 264 padded to 288 (divisible by BN=96)
#define MATSZ (NCOLS * NSER)      // elements per transposed mat buffer
#define PARTELEMS (NCOLS * NSER)  // fp32 partial buffer elements

__device__ __forceinline__ u16 f2bf(float f) {
  uint32_t u = __builtin_bit_cast(uint32_t, f);
  u += 0x7FFFu + ((u >> 16) & 1u);   // RNE; inputs are never NaN
  return (u16)(u >> 16);
}
__device__ __forceinline__ float bf2f(u16 h) {
  return __builtin_bit_cast(float, (uint32_t)h << 16);
}

typedef const void __attribute__((address_space(1)))* gas1p;
typedef void __attribute__((address_space(3)))* las3p;

__device__ __forceinline__ void gload16(const void* g, void* l) {
  __builtin_amdgcn_global_load_lds((gas1p)g, (las3p)l, 16, 0, 0);
}

// ---------------- convert supports fp32 -> bf16 (grid-stride, nt loads) ----------------
__global__ __launch_bounds__(256) void k_convert(const float* __restrict__ s0,
                                                 const float* __restrict__ s1,
                                                 u16* __restrict__ d0,
                                                 u16* __restrict__ d1) {
  const float* src = blockIdx.z ? s1 : s0;
  u16* dst = blockIdx.z ? d1 : d0;
  size_t i = ((size_t)blockIdx.x * 256 + threadIdx.x) * 8;
  const size_t stride = (size_t)gridDim.x * 256 * 8;
  #pragma unroll
  for (int it = 0; it < 4; ++it, i += stride) {
    f32x4 a = __builtin_nontemporal_load((const f32x4*)(src + i));
    f32x4 b = __builtin_nontemporal_load((const f32x4*)(src + i + 4));
    u16x8 o;
    o[0] = f2bf(a[0]); o[1] = f2bf(a[1]); o[2] = f2bf(a[2]); o[3] = f2bf(a[3]);
    o[4] = f2bf(b[0]); o[5] = f2bf(b[1]); o[6] = f2bf(b[2]); o[7] = f2bf(b[3]);
    *(u16x8*)(dst + i) = o;
  }
}

// ---------------- build X^T [288][4096] bf16 ----------------
// Xt[f*4+b][n] = xs[b,n,f];  f<2 -> inputs[b][n*2+f], f>=2 -> state[b][n*64+(f-2)]
__global__ __launch_bounds__(256) void k_build_x(const float* __restrict__ inputs,
                                                 const float* __restrict__ state,
                                                 u16* __restrict__ xb) {
  __shared__ float tile[64][65];
  const int nt = blockIdx.x, b = blockIdx.y;
  const int n0 = nt * 64;
  const int t = threadIdx.x;
  {
    const int i = t >> 2;
    const int c0 = (t & 3) * 16;
    const float* sp = state + ((int64_t)b * NSER + (n0 + i)) * 64 + c0;
    #pragma unroll
    for (int q = 0; q < 4; ++q) {
      float4 v = *(const float4*)(sp + q * 4);
      tile[i][c0 + q * 4 + 0] = v.x;
      tile[i][c0 + q * 4 + 1] = v.y;
      tile[i][c0 + q * 4 + 2] = v.z;
      tile[i][c0 + q * 4 + 3] = v.w;
    }
  }
  __syncthreads();
  const int wv = t >> 6, lane = t & 63;
  #pragma unroll
  for (int it = 0; it < 16; ++it) {
    const int d = wv + 4 * it;  // 0..63
    xb[(size_t)((2 + d) * 4 + b) * NSER + n0 + lane] = f2bf(tile[lane][d]);
  }
  if (t < 128) {
    const int c = t >> 6, j = t & 63;
    xb[(size_t)(c * 4 + b) * NSER + n0 + j] =
        f2bf(inputs[(int64_t)b * (NSER * 2) + (int64_t)(n0 + j) * 2 + c]);
  }
  if (b == 0) {  // zero pad rows 264..287
    for (int idx = t; idx < 24 * 64; idx += 256)
      xb[(size_t)(264 + idx / 64) * NSER + n0 + (idx & 63)] = 0;
  }
}

// ---------------- GEMM: C^T[j][i] = sum_k A[i][k] * B^T[j][k] (bf16, split-K) ----------------
#define BM 128
#define BN 96
#define BK 64
#define ABYTES (BM * BK * 2)      // 16384
#define BBYTES (BN * BK * 2)      // 12288
#define BUFSZ  (ABYTES + BBYTES)  // 28672

// KC = number of K-chunks. KC>1: write fp32 partials P[z][j][i]. KC==1: write bf16 direct.
template <int KC>
__global__ __launch_bounds__(256) void k_gemm(const u16* __restrict__ A0,
                                              const u16* __restrict__ A1,
                                              const u16* __restrict__ Bm,
                                              float* __restrict__ Pb,
                                              u16* __restrict__ C0,
                                              u16* __restrict__ C1) {
  int kc = blockIdx.z;
  int unit = 0;
  if (kc >= KC) { unit = 1; kc -= KC; }
  const u16* Am = unit ? A1 : A0;
  const int i0 = blockIdx.x * BM;   // row-tile fastest -> col-blocks of same A panel share XCD
  const int j0 = blockIdx.y * BN;
  const int t = threadIdx.x;
  const int wid = t >> 6, lane = t & 63;
  constexpr int NKT = KDIM / KC / BK;
  const int kbyte0 = kc * (KDIM / KC) * 2;

  __shared__ char smem[2 * BUFSZ];

  // staging source offsets (pre-swizzled global source, linear LDS dest)
  int a_src[4];
  #pragma unroll
  for (int s = 0; s < 4; ++s) {
    const int row = (wid * 4 + s) * 8 + (lane >> 3);        // 0..127
    a_src[s] = row * (KDIM * 2) + 16 * ((lane & 7) ^ (row & 7));
  }
  int b_src[3];
  #pragma unroll
  for (int s = 0; s < 3; ++s) {
    const int row = (wid * 3 + s) * 8 + (lane >> 3);        // 0..95
    b_src[s] = row * (KDIM * 2) + 16 * ((lane & 7) ^ (row & 7));
  }
  const char* Agbase = (const char*)Am + (int64_t)i0 * (KDIM * 2) + kbyte0;
  const char* Bgbase = (const char*)Bm + (int64_t)j0 * (KDIM * 2) + kbyte0;

  // fragment LDS read offsets (swizzled)
  int aoffs[4], axors[4];
  #pragma unroll
  for (int mf = 0; mf < 4; ++mf) {
    const int row = (wid >> 1) * 64 + mf * 16 + (lane & 15);
    aoffs[mf] = row * 128;
    axors[mf] = (row & 7) << 4;
  }
  int boffs[3], bxors[3];
  #pragma unroll
  for (int nf = 0; nf < 3; ++nf) {
    const int row = (wid & 1) * 48 + nf * 16 + (lane & 15);
    boffs[nf] = ABYTES + row * 128;
    bxors[nf] = (row & 7) << 4;
  }
  const int klane = (lane >> 4) * 16;

  f32x4 acc[4][3];
  #pragma unroll
  for (int mf = 0; mf < 4; ++mf)
    #pragma unroll
    for (int nf = 0; nf < 3; ++nf)
      acc[mf][nf] = (f32x4){0.f, 0.f, 0.f, 0.f};

  // prologue stage kt=0 into buf 0
  #pragma unroll
  for (int s = 0; s < 4; ++s)
    gload16(Agbase + a_src[s], smem + (wid * 4 + s) * 1024);
  #pragma unroll
  for (int s = 0; s < 3; ++s)
    gload16(Bgbase + b_src[s], smem + ABYTES + (wid * 3 + s) * 1024);
  __syncthreads();

  for (int kt = 0; kt < NKT; ++kt) {
    const int cur = kt & 1;
    if (kt + 1 < NKT) {
      const char* Ak = Agbase + (kt + 1) * (BK * 2);
      const char* Bk = Bgbase + (kt + 1) * (BK * 2);
      char* sbuf = smem + (cur ^ 1) * BUFSZ;
      #pragma unroll
      for (int s = 0; s < 4; ++s)
        gload16(Ak + a_src[s], sbuf + (wid * 4 + s) * 1024);
      #pragma unroll
      for (int s = 0; s < 3; ++s)
        gload16(Bk + b_src[s], sbuf + ABYTES + (wid * 3 + s) * 1024);
    }
    const char* sb = smem + cur * BUFSZ;
    #pragma unroll
    for (int kk = 0; kk < 2; ++kk) {
      const int kb = kk * 64 + klane;
      bf16x8 af[4], bfv[3];
      #pragma unroll
      for (int mf = 0; mf < 4; ++mf)
        af[mf] = *(const bf16x8*)(sb + aoffs[mf] + (kb ^ axors[mf]));
      #pragma unroll
      for (int nf = 0; nf < 3; ++nf)
        bfv[nf] = *(const bf16x8*)(sb + boffs[nf] + (kb ^ bxors[nf]));
      #pragma unroll
      for (int mf = 0; mf < 4; ++mf)
        #pragma unroll
        for (int nf = 0; nf < 3; ++nf)
          acc[mf][nf] = __builtin_amdgcn_mfma_f32_16x16x32_bf16(af[mf], bfv[nf],
                                                                acc[mf][nf], 0, 0, 0);
    }
    __syncthreads();
  }

  // epilogue (C/D frag: col(j)=lane&15, row(i)=(lane>>4)*4+r)
  if (KC == 1) {
    u16* Cm = unit ? C1 : C0;
    #pragma unroll
    for (int mf = 0; mf < 4; ++mf) {
      const int i = i0 + (wid >> 1) * 64 + mf * 16 + ((lane >> 4) << 2);
      #pragma unroll
      for (int nf = 0; nf < 3; ++nf) {
        const int j = j0 + (wid & 1) * 48 + nf * 16 + (lane & 15);
        u16x4 w;
        #pragma unroll
        for (int r = 0; r < 4; ++r) w[r] = f2bf(acc[mf][nf][r]);
        *(u16x4*)(Cm + (size_t)j * NSER + i) = w;
      }
    }
  } else {
    float* Pp = Pb + (size_t)blockIdx.z * PARTELEMS;
    #pragma unroll
    for (int mf = 0; mf < 4; ++mf) {
      const int i = i0 + (wid >> 1) * 64 + mf * 16 + ((lane >> 4) << 2);
      #pragma unroll
      for (int nf = 0; nf < 3; ++nf) {
        const int j = j0 + (wid & 1) * 48 + nf * 16 + (lane & 15);
        __builtin_nontemporal_store(acc[mf][nf], (f32x4*)(Pp + (size_t)j * NSER + i));
      }
    }
  }
}

// ---------------- reduce 4 fp32 partials -> bf16 mat ----------------
__global__ __launch_bounds__(256) void k_reduce(const float* __restrict__ P,
                                                u16* __restrict__ o0,
                                                u16* __restrict__ o1) {
  const float* p = P + (size_t)blockIdx.z * (4 * (size_t)PARTELEMS);
  u16* o = blockIdx.z ? o1 : o0;
  const size_t i = ((size_t)blockIdx.x * 256 + threadIdx.x) * 4;
  f32x4 s = __builtin_nontemporal_load((const f32x4*)(p + i));
  #pragma unroll
  for (int k = 1; k < 4; ++k)
    s += __builtin_nontemporal_load((const f32x4*)(p + (size_t)k * PARTELEMS + i));
  u16x4 w;
  #pragma unroll
  for (int r = 0; r < 4; ++r) w[r] = f2bf(s[r]);
  *(u16x4*)(o + i) = w;
}

// ---------------- final: out[b,n,o] = sum_{f,mat} Yt_mat[f*4+b][n] * W'[f*5+mat][o] + bias ----------------
__global__ __launch_bounds__(256) void k_final(const float* __restrict__ weight,
                                               const float* __restrict__ biases,
                                               const u16* __restrict__ mats,
                                               float* __restrict__ out) {
  __shared__ float w2[330][32];
  const int nt = blockIdx.x, b = blockIdx.y, oh = blockIdx.z;
  const int n0 = nt * 64;
  const int t = threadIdx.x;
  const int lane = t & 63, wv = t >> 6;
  {
    const int ol = t & 31;
    const int o = oh * 32 + ol;
    for (int f = t >> 5; f < 66; f += 8) {
      const float v0 = weight[(f * 5 + 0) * 64 + o];
      const float v1 = weight[(f * 5 + 1) * 64 + o];
      const float v2 = weight[(f * 5 + 2) * 64 + o];
      const float v3 = weight[(f * 5 + 3) * 64 + o];
      const float v4 = weight[(f * 5 + 4) * 64 + o];
      w2[f * 5 + 0][ol] = v0 - v2;   // X coefficient
      w2[f * 5 + 1][ol] = v1 - v4;   // m1
      w2[f * 5 + 2][ol] = 2.f * v2;  // m2
      w2[f * 5 + 3][ol] = v3;        // m3
      w2[f * 5 + 4][ol] = 2.f * v4;  // m4
    }
  }
  __syncthreads();
  const int ob = oh * 32 + wv * 8;
  float acc[8];
  #pragma unroll
  for (int i = 0; i < 8; ++i) acc[i] = biases[ob + i];
  for (int f = 0; f < 66; ++f) {
    #pragma unroll
    for (int mat = 0; mat < 5; ++mat) {
      const float y = bf2f(mats[(size_t)mat * MATSZ + (size_t)(f * 4 + b) * NSER + n0 + lane]);
      const float* wr = &w2[f * 5 + mat][wv * 8];
      #pragma unroll
      for (int i = 0; i < 8; ++i) acc[i] = fmaf(y, wr[i], acc[i]);
    }
  }
  float* op = out + (size_t)b * (NSER * 64) + (size_t)(n0 + lane) * 64 + ob;
  #pragma unroll
  for (int i = 0; i < 8; ++i) op[i] = acc[i];
}

extern "C" void kernel_launch(void* const* d_in, const int* in_sizes, int n_in,
                              void* d_out, int out_size, void* d_ws, size_t ws_size,
                              hipStream_t stream) {
  const float* inputs = (const float*)d_in[0];
  const float* state  = (const float*)d_in[1];
  const float* s0     = (const float*)d_in[2];
  const float* s1     = (const float*)d_in[3];
  const float* weight = (const float*)d_in[4];
  const float* biases = (const float*)d_in[5];
  float* out = (float*)d_out;

  char* ws = (char*)d_ws;
  u16* S0b = (u16*)ws;                                  // 33,554,432 B
  u16* S1b = (u16*)(ws + (size_t)33554432);             // 33,554,432 B
  u16* Xb  = (u16*)(ws + (size_t)67108864);             // 5 mats x 2,359,296 B
  u16* m1b = Xb  + MATSZ;
  u16* m2b = m1b + MATSZ;
  u16* m3b = m2b + MATSZ;
  u16* m4b = m3b + MATSZ;
  float* P = (float*)(ws + (size_t)(67108864 + 5 * 2359296));  // up to 8 x 4,718,592 B

  const size_t NEED_BIG = 67108864ull + 5ull * 2359296 + 8ull * 4718592;  // 116,654,080
  const size_t NEED_MID = 67108864ull + 5ull * 2359296 + 4ull * 4718592;  //  97,779,712

  k_convert<<<dim3(2048, 1, 2), 256, 0, stream>>>(s0, s1, S0b, S1b);
  k_build_x<<<dim3(64, 4, 1), 256, 0, stream>>>(inputs, state, Xb);

  if (ws_size >= NEED_BIG) {
    // m1 = S0 @ X
    k_gemm<4><<<dim3(32, 3, 4), 256, 0, stream>>>(S0b, S0b, Xb, P, nullptr, nullptr);
    k_reduce<<<dim3(1152, 1, 1), 256, 0, stream>>>(P, m1b, m1b);
    // m2 = S0 @ m1 ; m3 = S1 @ m1 (fused)
    k_gemm<4><<<dim3(32, 3, 8), 256, 0, stream>>>(S0b, S1b, m1b, P, nullptr, nullptr);
    k_reduce<<<dim3(1152, 1, 2), 256, 0, stream>>>(P, m2b, m3b);
    // m4 = S1 @ m3
    k_gemm<4><<<dim3(32, 3, 4), 256, 0, stream>>>(S1b, S1b, m3b, P, nullptr, nullptr);
    k_reduce<<<dim3(1152, 1, 1), 256, 0, stream>>>(P, m4b, m4b);
  } else if (ws_size >= NEED_MID) {
    k_gemm<4><<<dim3(32, 3, 4), 256, 0, stream>>>(S0b, S0b, Xb, P, nullptr, nullptr);
    k_reduce<<<dim3(1152, 1, 1), 256, 0, stream>>>(P, m1b, m1b);
    k_gemm<4><<<dim3(32, 3, 4), 256, 0, stream>>>(S0b, S0b, m1b, P, nullptr, nullptr);
    k_reduce<<<dim3(1152, 1, 1), 256, 0, stream>>>(P, m2b, m2b);
    k_gemm<4><<<dim3(32, 3, 4), 256, 0, stream>>>(S1b, S1b, m1b, P, nullptr, nullptr);
    k_reduce<<<dim3(1152, 1, 1), 256, 0, stream>>>(P, m3b, m3b);
    k_gemm<4><<<dim3(32, 3, 4), 256, 0, stream>>>(S1b, S1b, m3b, P, nullptr, nullptr);
    k_reduce<<<dim3(1152, 1, 1), 256, 0, stream>>>(P, m4b, m4b);
  } else {
    // round-1 direct path (no split-K)
    k_gemm<1><<<dim3(32, 3, 1), 256, 0, stream>>>(S0b, S0b, Xb, nullptr, m1b, m1b);
    k_gemm<1><<<dim3(32, 3, 2), 256, 0, stream>>>(S0b, S1b, m1b, nullptr, m2b, m3b);
    k_gemm<1><<<dim3(32, 3, 1), 256, 0, stream>>>(S1b, S1b, m3b, nullptr, m4b, m4b);
  }

  k_final<<<dim3(64, 4, 2), 256, 0, stream>>>(weight, biases, Xb, out);
}